// Round 3
// baseline (690.237 us; speedup 1.0000x reference)
//
#include <hip/hip_runtime.h>
#include <math.h>

#define LEVELS 16
#define HASHMAP_SIZE (1 << 19)
#define N_POINTS 2097152

typedef __attribute__((ext_vector_type(8))) short bf16x8;
typedef __attribute__((ext_vector_type(4))) float f32x4;

__device__ __forceinline__ unsigned short f2bf(float f) {
    unsigned u = __builtin_bit_cast(unsigned, f);
    u += 0x7FFFu + ((u >> 16) & 1u);   // RNE
    return (unsigned short)(u >> 16);
}

// LDS byte-swizzle (T2/G4): spread 128B-stride rows across banks for ds_read_b128
__device__ __forceinline__ unsigned swz(unsigned row, unsigned colbyte) {
    return row * 128u + (colbyte ^ ((row & 7u) << 4));
}

// Build a B-fragment (or A-side weight slice) from global f32 weights:
// element j <-> k = k0+j, column n of an [kmax x ncols] row-major matrix.
__device__ __forceinline__ bf16x8 load_wfrag(const float* __restrict__ W, int ncols,
                                             int n, int k0, int kmax) {
    bf16x8 r;
    #pragma unroll
    for (int j = 0; j < 8; ++j) {
        const int k = k0 + j;
        const float v = (k < kmax) ? W[k * ncols + n] : 0.f;
        r[j] = (short)f2bf(v);
    }
    return r;
}

__global__ __launch_bounds__(256, 5) void nerf_mfma2(
    const float* __restrict__ x,
    const float* __restrict__ view_dir,
    const float* __restrict__ tables,
    const float* __restrict__ W0, const float* __restrict__ b0,
    const float* __restrict__ W1, const float* __restrict__ b1,
    const float* __restrict__ W2, const float* __restrict__ b2,
    float* __restrict__ out)
{
    __shared__ __align__(16) unsigned short acts[256 * 64]; // 32 KB exactly; only LDS use
    char* const actsb = (char*)acts;

    const int tid = threadIdx.x;
    const int gid = blockIdx.x * 256 + tid;

    // ---- gather: one point per thread, build bf16 feature row in LDS ----
    const float px = x[gid * 3 + 0];
    const float py = x[gid * 3 + 1];
    const float pz = x[gid * 3 + 2];

    const float res[LEVELS] = {16.f, 24.f, 36.f, 54.f, 81.f, 121.f, 182.f, 273.f,
                               410.f, 615.f, 922.f, 1383.f, 2075.f, 3113.f, 4670.f, 7006.f};

    unsigned fw[18];
    #pragma unroll
    for (int l = 0; l < LEVELS; ++l) {
        const int ix = (int)floorf(px * res[l]);
        const int iy = (int)floorf(py * res[l]);
        const int iz = (int)floorf(pz * res[l]);
        const unsigned h = (unsigned)ix * 73856093u
                         ^ (unsigned)iy * 19349663u
                         ^ (unsigned)iz * 83492791u;
        const unsigned idx = h & (unsigned)(HASHMAP_SIZE - 1);
        const float2 f = *reinterpret_cast<const float2*>(
            tables + ((size_t)l * HASHMAP_SIZE + idx) * 2);
        fw[l] = (unsigned)f2bf(f.x) | ((unsigned)f2bf(f.y) << 16);
    }
    fw[16] = (unsigned)f2bf(view_dir[gid * 3 + 0])
           | ((unsigned)f2bf(view_dir[gid * 3 + 1]) << 16);
    fw[17] = (unsigned)f2bf(view_dir[gid * 3 + 2]);

    {
        const unsigned row = (unsigned)tid;
        #pragma unroll
        for (int c = 0; c < 8; ++c) {
            int4 v;
            if (c < 4)       v = make_int4((int)fw[4*c], (int)fw[4*c+1], (int)fw[4*c+2], (int)fw[4*c+3]);
            else if (c == 4) v = make_int4((int)fw[16], (int)fw[17], 0, 0);
            else             v = make_int4(0, 0, 0, 0);
            *(int4*)(actsb + swz(row, (unsigned)(c * 16))) = v;
        }
    }
    // No barriers anywhere: wave w reads/writes only rows [64w, 64w+64).

    const int lane = tid & 63;
    const int lr = lane & 15;                      // A row-in-tile / B col / C col
    const int lg = lane >> 4;                      // k-group / C row-group
    const unsigned Rbase = (unsigned)(tid & ~63);  // this wave's first row

    // ==== Layers 0 & 1: acts[256x64] @ W -> relu -> acts (in place) ====
    #pragma unroll
    for (int layer = 0; layer < 2; ++layer) {
        const float* const Wg = layer ? W1 : W0;
        const float* const bg = layer ? b1 : b0;
        const int kmax = layer ? 64 : 35;

        bf16x8 bw[8];
        #pragma unroll
        for (int nt = 0; nt < 4; ++nt)
            #pragma unroll
            for (int ks = 0; ks < 2; ++ks)
                bw[nt * 2 + ks] = load_wfrag(Wg, 64, nt * 16 + lr, ks * 32 + lg * 8, kmax);

        #pragma unroll
        for (int rt = 0; rt < 4; ++rt) {
            bf16x8 aa[2];
            #pragma unroll
            for (int ks = 0; ks < 2; ++ks) {
                const unsigned row = Rbase + (unsigned)(rt * 16 + lr);
                aa[ks] = *(const bf16x8*)(actsb + swz(row, (unsigned)((ks * 4 + lg) * 16)));
            }
            #pragma unroll
            for (int nt = 0; nt < 4; ++nt) {
                const float bv = bg[nt * 16 + lr];
                f32x4 c = {bv, bv, bv, bv};
                c = __builtin_amdgcn_mfma_f32_16x16x32_bf16(aa[0], bw[nt * 2 + 0], c, 0, 0, 0);
                c = __builtin_amdgcn_mfma_f32_16x16x32_bf16(aa[1], bw[nt * 2 + 1], c, 0, 0, 0);
                #pragma unroll
                for (int r = 0; r < 4; ++r) {
                    const float v = fmaxf(c[r], 0.f);
                    const unsigned row = Rbase + (unsigned)(rt * 16 + lg * 4 + r);
                    const unsigned col = (unsigned)(nt * 16 + lr);
                    *(unsigned short*)(actsb + swz(row, col * 2)) = f2bf(v);
                }
            }
        }
    }

    // ==== Layer 2 (64 -> 4) on MFMA: out cols 0..3 valid ====
    {
        const bool valid = (lr < 4);
        bf16x8 bw2[2];
        #pragma unroll
        for (int ks = 0; ks < 2; ++ks) {
            if (valid) bw2[ks] = load_wfrag(W2, 4, lr, ks * 32 + lg * 8, 64);
            else       bw2[ks] = bf16x8{0,0,0,0,0,0,0,0};
        }
        const float bc = valid ? b2[lr] : 0.f;

        #pragma unroll
        for (int rt = 0; rt < 4; ++rt) {
            bf16x8 aa[2];
            #pragma unroll
            for (int ks = 0; ks < 2; ++ks) {
                const unsigned row = Rbase + (unsigned)(rt * 16 + lr);
                aa[ks] = *(const bf16x8*)(actsb + swz(row, (unsigned)((ks * 4 + lg) * 16)));
            }
            f32x4 c = {bc, bc, bc, bc};
            c = __builtin_amdgcn_mfma_f32_16x16x32_bf16(aa[0], bw2[0], c, 0, 0, 0);
            c = __builtin_amdgcn_mfma_f32_16x16x32_bf16(aa[1], bw2[1], c, 0, 0, 0);
            #pragma unroll
            for (int r = 0; r < 4; ++r) {
                const unsigned grow = (unsigned)(blockIdx.x * 256) + Rbase
                                    + (unsigned)(rt * 16 + lg * 4 + r);
                const float v = c[r];
                if (lr < 3)       out[(size_t)grow * 3 + lr] = 1.f / (1.f + __expf(-v));
                else if (lr == 3) out[(size_t)N_POINTS * 3 + grow] = fmaxf(v, 0.f);
            }
        }
    }
}

extern "C" void kernel_launch(void* const* d_in, const int* in_sizes, int n_in,
                              void* d_out, int out_size, void* d_ws, size_t ws_size,
                              hipStream_t stream) {
    (void)in_sizes; (void)n_in; (void)d_ws; (void)ws_size; (void)out_size;
    const float* x        = (const float*)d_in[0];
    const float* view_dir = (const float*)d_in[1];
    const float* tables   = (const float*)d_in[2];
    const float* W0       = (const float*)d_in[3];
    const float* b0       = (const float*)d_in[4];
    const float* W1       = (const float*)d_in[5];
    const float* b1       = (const float*)d_in[6];
    const float* W2       = (const float*)d_in[7];
    const float* b2       = (const float*)d_in[8];
    float* out = (float*)d_out;

    const int block = 256;
    const int grid = N_POINTS / block;  // 8192
    nerf_mfma2<<<grid, block, 0, stream>>>(x, view_dir, tables,
                                           W0, b0, W1, b1, W2, b2, out);
}

// Round 4
// 547.497 us; speedup vs baseline: 1.2607x; 1.2607x over previous
//
#include <hip/hip_runtime.h>
#include <math.h>

#define LEVELS 16
#define HASHMAP_SIZE (1 << 19)
#define N_POINTS 2097152

typedef __attribute__((ext_vector_type(8))) short bf16x8;
typedef __attribute__((ext_vector_type(4))) float f32x4;

__device__ __forceinline__ unsigned short f2bf(float f) {
    unsigned u = __builtin_bit_cast(unsigned, f);
    u += 0x7FFFu + ((u >> 16) & 1u);   // RNE
    return (unsigned short)(u >> 16);
}
__device__ __forceinline__ float bf2f(unsigned short s) {
    unsigned u = ((unsigned)s) << 16;
    return __builtin_bit_cast(float, u);
}

// LDS byte-swizzle (T2/G4): spread 128B-stride rows across banks for ds_read_b128
__device__ __forceinline__ unsigned swz(unsigned row, unsigned colbyte) {
    return row * 128u + (colbyte ^ ((row & 7u) << 4));
}

// B-fragment from global f32 weights: element j <-> k=k0+j, column n of [kmax x ncols] row-major.
__device__ __forceinline__ bf16x8 load_wfrag(const float* __restrict__ W, int ncols,
                                             int n, int k0, int kmax) {
    bf16x8 r;
    #pragma unroll
    for (int j = 0; j < 8; ++j) {
        const int k = k0 + j;
        const float v = (k < kmax) ? W[k * ncols + n] : 0.f;
        r[j] = (short)f2bf(v);
    }
    return r;
}

__global__ __launch_bounds__(256, 4) void nerf_mfma3(
    const float* __restrict__ x,
    const float* __restrict__ view_dir,
    const float* __restrict__ tables,
    const float* __restrict__ W0, const float* __restrict__ b0,
    const float* __restrict__ W1, const float* __restrict__ b1,
    const float* __restrict__ W2, const float* __restrict__ b2,
    float* __restrict__ out)
{
    __shared__ __align__(16) unsigned short acts[256 * 64]; // 32 KB; only LDS use
    char* const actsb = (char*)acts;

    const int tid = threadIdx.x;
    const int gid = blockIdx.x * 256 + tid;

    const float px = x[gid * 3 + 0];
    const float py = x[gid * 3 + 1];
    const float pz = x[gid * 3 + 2];

    const float res[LEVELS] = {16.f, 24.f, 36.f, 54.f, 81.f, 121.f, 182.f, 273.f,
                               410.f, 615.f, 922.f, 1383.f, 2075.f, 3113.f, 4670.f, 7006.f};

    // ---- compute all hash indices first, then issue all 16 loads back-to-back ----
    unsigned idx[LEVELS];
    #pragma unroll
    for (int l = 0; l < LEVELS; ++l) {
        const int ix = (int)floorf(px * res[l]);
        const int iy = (int)floorf(py * res[l]);
        const int iz = (int)floorf(pz * res[l]);
        const unsigned h = (unsigned)ix * 73856093u
                         ^ (unsigned)iy * 19349663u
                         ^ (unsigned)iz * 83492791u;
        idx[l] = h & (unsigned)(HASHMAP_SIZE - 1);
    }
    float2 f[LEVELS];
    #pragma unroll
    for (int l = 0; l < LEVELS; ++l)
        f[l] = *reinterpret_cast<const float2*>(
            tables + ((size_t)l * HASHMAP_SIZE + idx[l]) * 2);

    const float v0 = view_dir[gid * 3 + 0];
    const float v1 = view_dir[gid * 3 + 1];
    const float v2 = view_dir[gid * 3 + 2];

    // ---- pack row (bf16) into swizzled LDS ----
    {
        const unsigned row = (unsigned)tid;
        unsigned fw[18];
        #pragma unroll
        for (int l = 0; l < LEVELS; ++l)
            fw[l] = (unsigned)f2bf(f[l].x) | ((unsigned)f2bf(f[l].y) << 16);
        fw[16] = (unsigned)f2bf(v0) | ((unsigned)f2bf(v1) << 16);
        fw[17] = (unsigned)f2bf(v2);
        #pragma unroll
        for (int c = 0; c < 8; ++c) {
            int4 v;
            if (c < 4)       v = make_int4((int)fw[4*c], (int)fw[4*c+1], (int)fw[4*c+2], (int)fw[4*c+3]);
            else if (c == 4) v = make_int4((int)fw[16], (int)fw[17], 0, 0);
            else             v = make_int4(0, 0, 0, 0);
            *(int4*)(actsb + swz(row, (unsigned)(c * 16))) = v;
        }
    }
    // No barriers anywhere: wave w reads/writes only rows [64w, 64w+64).

    const int lane = tid & 63;
    const int lr = lane & 15;                      // A row-in-tile / B col / C col
    const int lg = lane >> 4;                      // k-group / C row-group
    const unsigned Rbase = (unsigned)(tid & ~63);  // this wave's first row

    // ==== Layers 0 & 1: acts[256x64] @ W -> relu -> acts (in place) ====
    #pragma unroll
    for (int layer = 0; layer < 2; ++layer) {
        const float* const Wg = layer ? W1 : W0;
        const float* const bg = layer ? b1 : b0;
        const int kmax = layer ? 64 : 35;

        bf16x8 bw[8];
        #pragma unroll
        for (int nt = 0; nt < 4; ++nt)
            #pragma unroll
            for (int ks = 0; ks < 2; ++ks)
                bw[nt * 2 + ks] = load_wfrag(Wg, 64, nt * 16 + lr, ks * 32 + lg * 8, kmax);

        #pragma unroll
        for (int rt = 0; rt < 4; ++rt) {
            bf16x8 aa[2];
            #pragma unroll
            for (int ks = 0; ks < 2; ++ks) {
                const unsigned row = Rbase + (unsigned)(rt * 16 + lr);
                aa[ks] = *(const bf16x8*)(actsb + swz(row, (unsigned)((ks * 4 + lg) * 16)));
            }
            #pragma unroll
            for (int nt = 0; nt < 4; ++nt) {
                const float bv = bg[nt * 16 + lr];
                f32x4 c = {bv, bv, bv, bv};
                c = __builtin_amdgcn_mfma_f32_16x16x32_bf16(aa[0], bw[nt * 2 + 0], c, 0, 0, 0);
                c = __builtin_amdgcn_mfma_f32_16x16x32_bf16(aa[1], bw[nt * 2 + 1], c, 0, 0, 0);
                #pragma unroll
                for (int r = 0; r < 4; ++r) {
                    const float v = fmaxf(c[r], 0.f);
                    const unsigned row = Rbase + (unsigned)(rt * 16 + lg * 4 + r);
                    const unsigned col = (unsigned)(nt * 16 + lr);
                    *(unsigned short*)(actsb + swz(row, col * 2)) = f2bf(v);
                }
            }
        }
    }

    // ==== Layer 2 (64 -> 4): per-thread, wave-uniform W2 (scalar loads), coalesced stores ====
    {
        float o0 = b2[0], o1 = b2[1], o2 = b2[2], o3 = b2[3];
        const unsigned row = (unsigned)tid;
        #pragma unroll
        for (int c = 0; c < 8; ++c) {
            const bf16x8 v = *(const bf16x8*)(actsb + swz(row, (unsigned)(c * 16)));
            #pragma unroll
            for (int j = 0; j < 8; ++j) {
                const float s = bf2f((unsigned short)v[j]);
                const int k = c * 8 + j;
                o0 += s * W2[k * 4 + 0];
                o1 += s * W2[k * 4 + 1];
                o2 += s * W2[k * 4 + 2];
                o3 += s * W2[k * 4 + 3];
            }
        }
        out[(size_t)gid * 3 + 0] = 1.f / (1.f + __expf(-o0));
        out[(size_t)gid * 3 + 1] = 1.f / (1.f + __expf(-o1));
        out[(size_t)gid * 3 + 2] = 1.f / (1.f + __expf(-o2));
        out[(size_t)N_POINTS * 3 + gid] = fmaxf(o3, 0.f);
    }
}

extern "C" void kernel_launch(void* const* d_in, const int* in_sizes, int n_in,
                              void* d_out, int out_size, void* d_ws, size_t ws_size,
                              hipStream_t stream) {
    (void)in_sizes; (void)n_in; (void)d_ws; (void)ws_size; (void)out_size;
    const float* x        = (const float*)d_in[0];
    const float* view_dir = (const float*)d_in[1];
    const float* tables   = (const float*)d_in[2];
    const float* W0       = (const float*)d_in[3];
    const float* b0       = (const float*)d_in[4];
    const float* W1       = (const float*)d_in[5];
    const float* b1       = (const float*)d_in[6];
    const float* W2       = (const float*)d_in[7];
    const float* b2       = (const float*)d_in[8];
    float* out = (float*)d_out;

    const int block = 256;
    const int grid = N_POINTS / block;  // 8192
    nerf_mfma3<<<grid, block, 0, stream>>>(x, view_dir, tables,
                                           W0, b0, W1, b1, W2, b2, out);
}

// Round 5
// 324.581 us; speedup vs baseline: 2.1265x; 1.6868x over previous
//
#include <hip/hip_runtime.h>
#include <math.h>

#define LEVELS 16
#define HASHMAP_SIZE (1 << 19)
#define N_POINTS 2097152

typedef __attribute__((ext_vector_type(8))) short bf16x8;
typedef __attribute__((ext_vector_type(4))) float f32x4;

__device__ __constant__ float c_res[LEVELS] = {
    16.f, 24.f, 36.f, 54.f, 81.f, 121.f, 182.f, 273.f,
    410.f, 615.f, 922.f, 1383.f, 2075.f, 3113.f, 4670.f, 7006.f};

__device__ __forceinline__ unsigned short f2bf(float f) {
    unsigned u = __builtin_bit_cast(unsigned, f);
    u += 0x7FFFu + ((u >> 16) & 1u);   // RNE
    return (unsigned short)(u >> 16);
}
__device__ __forceinline__ float bf2f(unsigned short s) {
    unsigned u = ((unsigned)s) << 16;
    return __builtin_bit_cast(float, u);
}

// LDS byte-swizzle (T2/G4)
__device__ __forceinline__ unsigned swz(unsigned row, unsigned colbyte) {
    return row * 128u + (colbyte ^ ((row & 7u) << 4));
}

__device__ __forceinline__ unsigned hash3(float px, float py, float pz, float r) {
    const int ix = (int)floorf(px * r);
    const int iy = (int)floorf(py * r);
    const int iz = (int)floorf(pz * r);
    const unsigned h = (unsigned)ix * 73856093u
                     ^ (unsigned)iy * 19349663u
                     ^ (unsigned)iz * 83492791u;
    return h & (unsigned)(HASHMAP_SIZE - 1);
}

__device__ __forceinline__ bf16x8 load_wfrag(const float* __restrict__ W, int ncols,
                                             int n, int k0, int kmax) {
    bf16x8 r;
    #pragma unroll
    for (int j = 0; j < 8; ++j) {
        const int k = k0 + j;
        const float v = (k < kmax) ? W[k * ncols + n] : 0.f;
        r[j] = (short)f2bf(v);
    }
    return r;
}

// ===================== Pass A0: tables f32 -> packed bf16x2 =====================
__global__ __launch_bounds__(256) void conv_tables(const float* __restrict__ tables,
                                                   unsigned* __restrict__ tabp) {
    const int t = blockIdx.x * 256 + threadIdx.x;   // 2097152 threads, 4 entries each
    const float4 a = *reinterpret_cast<const float4*>(tables + (size_t)t * 8);
    const float4 b = *reinterpret_cast<const float4*>(tables + (size_t)t * 8 + 4);
    uint4 o;
    o.x = (unsigned)f2bf(a.x) | ((unsigned)f2bf(a.y) << 16);
    o.y = (unsigned)f2bf(a.z) | ((unsigned)f2bf(a.w) << 16);
    o.z = (unsigned)f2bf(b.x) | ((unsigned)f2bf(b.y) << 16);
    o.w = (unsigned)f2bf(b.z) | ((unsigned)f2bf(b.w) << 16);
    *reinterpret_cast<uint4*>(tabp + (size_t)t * 4) = o;
}

// ===================== Pass A1: XCD-pinned gather =====================
// grid = 8 pairs * (chunkpts/1024); pair = blockIdx & 7 -> XCD (round-robin dispatch).
// pair p serves levels {p, p+8}; bf16 footprint 2x2MB = 4MB = one XCD L2.
__global__ __launch_bounds__(256) void nerf_gather(
    const float* __restrict__ x,
    const unsigned* __restrict__ tabp,
    unsigned* __restrict__ feat,
    int chunkbase, int chunkpts)
{
    const int b = blockIdx.x;
    const int pair = b & 7;
    const int chunkblk = b >> 3;
    const int l0 = pair, l1 = pair + 8;
    const float r0 = c_res[l0], r1 = c_res[l1];
    const int tid = threadIdx.x;
    const int pbase = chunkblk * 1024;

    unsigned idxA[4], idxB[4];
    #pragma unroll
    for (int i = 0; i < 4; ++i) {
        const int pl = pbase + i * 256 + tid;
        const size_t pg = (size_t)chunkbase + pl;
        const float px = x[pg * 3 + 0];
        const float py = x[pg * 3 + 1];
        const float pz = x[pg * 3 + 2];
        idxA[i] = hash3(px, py, pz, r0);
        idxB[i] = hash3(px, py, pz, r1);
    }
    unsigned gA[4], gB[4];
    #pragma unroll
    for (int i = 0; i < 4; ++i) {
        gA[i] = tabp[(size_t)l0 * HASHMAP_SIZE + idxA[i]];
        gB[i] = tabp[(size_t)l1 * HASHMAP_SIZE + idxB[i]];
    }
    #pragma unroll
    for (int i = 0; i < 4; ++i) {
        const int pl = pbase + i * 256 + tid;
        feat[(size_t)l0 * chunkpts + pl] = gA[i];
        feat[(size_t)l1 * chunkpts + pl] = gB[i];
    }
}

// ===================== Pass B: MLP on MFMA =====================
__global__ __launch_bounds__(256, 4) void nerf_mlp(
    const unsigned* __restrict__ feat,
    const float* __restrict__ view_dir,
    const float* __restrict__ W0, const float* __restrict__ b0,
    const float* __restrict__ W1, const float* __restrict__ b1,
    const float* __restrict__ W2, const float* __restrict__ b2,
    float* __restrict__ out,
    int chunkbase, int chunkpts)
{
    __shared__ __align__(16) unsigned short acts[256 * 64]; // 32 KB
    char* const actsb = (char*)acts;

    const int tid = threadIdx.x;
    const int gl = blockIdx.x * 256 + tid;          // local point
    const size_t gid = (size_t)chunkbase + gl;       // global point

    unsigned fw[18];
    #pragma unroll
    for (int l = 0; l < LEVELS; ++l)
        fw[l] = feat[(size_t)l * chunkpts + gl];
    fw[16] = (unsigned)f2bf(view_dir[gid * 3 + 0])
           | ((unsigned)f2bf(view_dir[gid * 3 + 1]) << 16);
    fw[17] = (unsigned)f2bf(view_dir[gid * 3 + 2]);

    {
        const unsigned row = (unsigned)tid;
        #pragma unroll
        for (int c = 0; c < 8; ++c) {
            int4 v;
            if (c < 4)       v = make_int4((int)fw[4*c], (int)fw[4*c+1], (int)fw[4*c+2], (int)fw[4*c+3]);
            else if (c == 4) v = make_int4((int)fw[16], (int)fw[17], 0, 0);
            else             v = make_int4(0, 0, 0, 0);
            *(int4*)(actsb + swz(row, (unsigned)(c * 16))) = v;
        }
    }
    // No barriers: wave w touches only rows [64w, 64w+64).

    const int lane = tid & 63;
    const int lr = lane & 15;
    const int lg = lane >> 4;
    const unsigned Rbase = (unsigned)(tid & ~63);

    #pragma unroll
    for (int layer = 0; layer < 2; ++layer) {
        const float* const Wg = layer ? W1 : W0;
        const float* const bg = layer ? b1 : b0;
        const int kmax = layer ? 64 : 35;

        bf16x8 bw[8];
        #pragma unroll
        for (int nt = 0; nt < 4; ++nt)
            #pragma unroll
            for (int ks = 0; ks < 2; ++ks)
                bw[nt * 2 + ks] = load_wfrag(Wg, 64, nt * 16 + lr, ks * 32 + lg * 8, kmax);

        #pragma unroll
        for (int rt = 0; rt < 4; ++rt) {
            bf16x8 aa[2];
            #pragma unroll
            for (int ks = 0; ks < 2; ++ks) {
                const unsigned row = Rbase + (unsigned)(rt * 16 + lr);
                aa[ks] = *(const bf16x8*)(actsb + swz(row, (unsigned)((ks * 4 + lg) * 16)));
            }
            #pragma unroll
            for (int nt = 0; nt < 4; ++nt) {
                const float bv = bg[nt * 16 + lr];
                f32x4 c = {bv, bv, bv, bv};
                c = __builtin_amdgcn_mfma_f32_16x16x32_bf16(aa[0], bw[nt * 2 + 0], c, 0, 0, 0);
                c = __builtin_amdgcn_mfma_f32_16x16x32_bf16(aa[1], bw[nt * 2 + 1], c, 0, 0, 0);
                #pragma unroll
                for (int r = 0; r < 4; ++r) {
                    const float v = fmaxf(c[r], 0.f);
                    const unsigned row = Rbase + (unsigned)(rt * 16 + lg * 4 + r);
                    const unsigned col = (unsigned)(nt * 16 + lr);
                    *(unsigned short*)(actsb + swz(row, col * 2)) = f2bf(v);
                }
            }
        }
    }

    {
        float o0 = b2[0], o1 = b2[1], o2 = b2[2], o3 = b2[3];
        const unsigned row = (unsigned)tid;
        #pragma unroll
        for (int c = 0; c < 8; ++c) {
            const bf16x8 v = *(const bf16x8*)(actsb + swz(row, (unsigned)(c * 16)));
            #pragma unroll
            for (int j = 0; j < 8; ++j) {
                const float s = bf2f((unsigned short)v[j]);
                const int k = c * 8 + j;
                o0 += s * W2[k * 4 + 0];
                o1 += s * W2[k * 4 + 1];
                o2 += s * W2[k * 4 + 2];
                o3 += s * W2[k * 4 + 3];
            }
        }
        out[gid * 3 + 0] = 1.f / (1.f + __expf(-o0));
        out[gid * 3 + 1] = 1.f / (1.f + __expf(-o1));
        out[gid * 3 + 2] = 1.f / (1.f + __expf(-o2));
        out[(size_t)N_POINTS * 3 + gid] = fmaxf(o3, 0.f);
    }
}

// ===================== Fallback: fused R4 kernel =====================
__global__ __launch_bounds__(256, 4) void nerf_fused(
    const float* __restrict__ x,
    const float* __restrict__ view_dir,
    const float* __restrict__ tables,
    const float* __restrict__ W0, const float* __restrict__ b0,
    const float* __restrict__ W1, const float* __restrict__ b1,
    const float* __restrict__ W2, const float* __restrict__ b2,
    float* __restrict__ out)
{
    __shared__ __align__(16) unsigned short acts[256 * 64];
    char* const actsb = (char*)acts;
    const int tid = threadIdx.x;
    const int gid = blockIdx.x * 256 + tid;
    const float px = x[gid * 3 + 0], py = x[gid * 3 + 1], pz = x[gid * 3 + 2];

    unsigned idx[LEVELS];
    #pragma unroll
    for (int l = 0; l < LEVELS; ++l) idx[l] = hash3(px, py, pz, c_res[l]);
    float2 f[LEVELS];
    #pragma unroll
    for (int l = 0; l < LEVELS; ++l)
        f[l] = *reinterpret_cast<const float2*>(tables + ((size_t)l * HASHMAP_SIZE + idx[l]) * 2);

    unsigned fw[18];
    #pragma unroll
    for (int l = 0; l < LEVELS; ++l)
        fw[l] = (unsigned)f2bf(f[l].x) | ((unsigned)f2bf(f[l].y) << 16);
    fw[16] = (unsigned)f2bf(view_dir[gid * 3 + 0])
           | ((unsigned)f2bf(view_dir[gid * 3 + 1]) << 16);
    fw[17] = (unsigned)f2bf(view_dir[gid * 3 + 2]);
    {
        const unsigned row = (unsigned)tid;
        #pragma unroll
        for (int c = 0; c < 8; ++c) {
            int4 v;
            if (c < 4)       v = make_int4((int)fw[4*c], (int)fw[4*c+1], (int)fw[4*c+2], (int)fw[4*c+3]);
            else if (c == 4) v = make_int4((int)fw[16], (int)fw[17], 0, 0);
            else             v = make_int4(0, 0, 0, 0);
            *(int4*)(actsb + swz(row, (unsigned)(c * 16))) = v;
        }
    }
    const int lane = tid & 63;
    const int lr = lane & 15;
    const int lg = lane >> 4;
    const unsigned Rbase = (unsigned)(tid & ~63);
    #pragma unroll
    for (int layer = 0; layer < 2; ++layer) {
        const float* const Wg = layer ? W1 : W0;
        const float* const bg = layer ? b1 : b0;
        const int kmax = layer ? 64 : 35;
        bf16x8 bw[8];
        #pragma unroll
        for (int nt = 0; nt < 4; ++nt)
            #pragma unroll
            for (int ks = 0; ks < 2; ++ks)
                bw[nt * 2 + ks] = load_wfrag(Wg, 64, nt * 16 + lr, ks * 32 + lg * 8, kmax);
        #pragma unroll
        for (int rt = 0; rt < 4; ++rt) {
            bf16x8 aa[2];
            #pragma unroll
            for (int ks = 0; ks < 2; ++ks) {
                const unsigned row = Rbase + (unsigned)(rt * 16 + lr);
                aa[ks] = *(const bf16x8*)(actsb + swz(row, (unsigned)((ks * 4 + lg) * 16)));
            }
            #pragma unroll
            for (int nt = 0; nt < 4; ++nt) {
                const float bv = bg[nt * 16 + lr];
                f32x4 c = {bv, bv, bv, bv};
                c = __builtin_amdgcn_mfma_f32_16x16x32_bf16(aa[0], bw[nt * 2 + 0], c, 0, 0, 0);
                c = __builtin_amdgcn_mfma_f32_16x16x32_bf16(aa[1], bw[nt * 2 + 1], c, 0, 0, 0);
                #pragma unroll
                for (int r = 0; r < 4; ++r) {
                    const float v = fmaxf(c[r], 0.f);
                    const unsigned row = Rbase + (unsigned)(rt * 16 + lg * 4 + r);
                    const unsigned col = (unsigned)(nt * 16 + lr);
                    *(unsigned short*)(actsb + swz(row, col * 2)) = f2bf(v);
                }
            }
        }
    }
    {
        float o0 = b2[0], o1 = b2[1], o2 = b2[2], o3 = b2[3];
        const unsigned row = (unsigned)tid;
        #pragma unroll
        for (int c = 0; c < 8; ++c) {
            const bf16x8 v = *(const bf16x8*)(actsb + swz(row, (unsigned)(c * 16)));
            #pragma unroll
            for (int j = 0; j < 8; ++j) {
                const float s = bf2f((unsigned short)v[j]);
                const int k = c * 8 + j;
                o0 += s * W2[k * 4 + 0];
                o1 += s * W2[k * 4 + 1];
                o2 += s * W2[k * 4 + 2];
                o3 += s * W2[k * 4 + 3];
            }
        }
        out[(size_t)gid * 3 + 0] = 1.f / (1.f + __expf(-o0));
        out[(size_t)gid * 3 + 1] = 1.f / (1.f + __expf(-o1));
        out[(size_t)gid * 3 + 2] = 1.f / (1.f + __expf(-o2));
        out[(size_t)N_POINTS * 3 + gid] = fmaxf(o3, 0.f);
    }
}

extern "C" void kernel_launch(void* const* d_in, const int* in_sizes, int n_in,
                              void* d_out, int out_size, void* d_ws, size_t ws_size,
                              hipStream_t stream) {
    (void)in_sizes; (void)n_in; (void)out_size;
    const float* x        = (const float*)d_in[0];
    const float* view_dir = (const float*)d_in[1];
    const float* tables   = (const float*)d_in[2];
    const float* W0       = (const float*)d_in[3];
    const float* b0       = (const float*)d_in[4];
    const float* W1       = (const float*)d_in[5];
    const float* b1       = (const float*)d_in[6];
    const float* W2       = (const float*)d_in[7];
    const float* b2       = (const float*)d_in[8];
    float* out = (float*)d_out;

    const size_t TAB_BYTES = (size_t)LEVELS * HASHMAP_SIZE * 4;  // 32 MB packed bf16

    int nchunks = 0;
    if      (ws_size >= TAB_BYTES + (size_t)N_POINTS * 64)      nchunks = 1;  // 160 MB
    else if (ws_size >= TAB_BYTES + (size_t)N_POINTS * 32)      nchunks = 2;  //  96 MB
    else if (ws_size >= TAB_BYTES + (size_t)N_POINTS * 16)      nchunks = 4;  //  64 MB

    if (nchunks == 0) {
        nerf_fused<<<N_POINTS / 256, 256, 0, stream>>>(x, view_dir, tables,
                                                       W0, b0, W1, b1, W2, b2, out);
        return;
    }

    unsigned* tabp = (unsigned*)d_ws;
    unsigned* feat = (unsigned*)((char*)d_ws + TAB_BYTES);
    const int chunkpts = N_POINTS / nchunks;

    conv_tables<<<(LEVELS * HASHMAP_SIZE / 4) / 256, 256, 0, stream>>>(tables, tabp);

    for (int c = 0; c < nchunks; ++c) {
        const int base = c * chunkpts;
        nerf_gather<<<8 * (chunkpts / 1024), 256, 0, stream>>>(x, tabp, feat, base, chunkpts);
        nerf_mlp<<<chunkpts / 256, 256, 0, stream>>>(feat, view_dir,
                                                     W0, b0, W1, b1, W2, b2, out,
                                                     base, chunkpts);
    }
}